// Round 2
// baseline (207.797 us; speedup 1.0000x reference)
//
#include <hip/hip_runtime.h>
#include <math.h>

typedef __bf16 bf16x8 __attribute__((ext_vector_type(8)));
typedef float f32x16 __attribute__((ext_vector_type(16)));

#define NTOK 131072
#define HDIM 128
#define ODIM 128
#define NEXP 8
// K padded to 9 kt-steps of 16: kt 0..7 = real H, kt 8 = bias row (x side = 1.0)

__device__ __forceinline__ unsigned short f2bf(float f){
  union { float f; unsigned u; } v; v.f = f;
  unsigned r = v.u + 0x7FFFu + ((v.u >> 16) & 1u);
  return (unsigned short)(r >> 16);
}

// ---------------------------------------------------------------------------
// Kernel 1: pack W into A-operand fragment layout (transposed GEMM: A[m=o][k=h])
// pw flat: [e][mt(4)][kt(9)][lane(64)][j(8)] bf16
// A-frag (v_mfma_f32_32x32x16_bf16): A[m=lane&31][k=(lane>>5)*8+j]
// kt==8: k-local 0 row = b_expert[e][o], rest zero.
__global__ void pack_w(const float* __restrict__ we, const float* __restrict__ be,
                       unsigned short* __restrict__ pw){
  int f = blockIdx.x * 256 + threadIdx.x;      // 0..18431
  int l  = f & 63;
  int kt = (f >> 6) % 9;
  int emt = f / (64 * 9);
  int mt = emt & 3;
  int e  = emt >> 2;
  int o  = (mt << 5) + (l & 31);
  unsigned short vals[8];
#pragma unroll
  for (int j = 0; j < 8; ++j){
    int kl = ((l >> 5) << 3) + j;
    float v;
    if (kt < 8){
      int h = kt * 16 + kl;
      v = we[(e * HDIM + h) * ODIM + o];
    } else {
      v = (kl == 0) ? be[e * ODIM + o] : 0.0f;
    }
    vals[j] = f2bf(v);
  }
  *(bf16x8*)(pw + (size_t)f * 8) = *(bf16x8*)vals;
}

// ---------------------------------------------------------------------------
// Kernel 2: FUSED gating + MoE FFN. 64 tokens/block, 256 threads (4 waves).
// LDS 39 KiB: xs f32 (33 KiB; later overlaid by bf16 frags (18 KiB), then by
// f32 transpose buf (32 KiB)) + wgt 4 KiB ([e][h] transposed, reads broadcast)
// + glds 2 KiB ([e][token]; holds logits, then overwritten in-place by gates).
// R5 change (occupancy round): the kernel is latency-bound at 2 blocks/CU
// (all pipes ~20%). Regs were the limiter (116 VGPR + ~96 AGPR): xb frags
// held 72 regs across the whole e-loop, unroll-2 doubled p0/p1. Fix: read
// B-frags from LDS inside the e-loop (conflict-free 1KB-contiguous tiles),
// revert to unroll 1, launch_bounds(256,4) -> 4 blocks/CU (LDS fits exactly:
// 4 x 39936 = 156 KiB). Spill tripwire: WRITE_SIZE must stay 65536 KB.
// CRITICAL (R1-R3 lesson): accumulators are NAMED vars (tot0/tot1), every loop
// touching register arrays fully unrolled — dynamic indexing put tot in scratch
// (537 MB/launch of spill writes = the entire mystery WRITE_SIZE).
__launch_bounds__(256, 4)
__global__ void moe_fused(const float* __restrict__ x, const float* __restrict__ wg,
                          const unsigned short* __restrict__ pw, float* __restrict__ out){
  __shared__ char lds[33792 + 4096 + 2048];
  float* xs            = (float*)lds;                 // [tok(64)][132] f32
  unsigned short* frag = (unsigned short*)lds;        // overlay: [tg2][kt9][l64][j8]
  float* tb            = (float*)lds;                 // overlay: [trow64][128] f32
  float* wgt           = (float*)(lds + 33792);       // [e8][h128] f32 (transposed)
  float* glds          = (float*)(lds + 33792 + 4096);// [e8][tok64] f32

  int t = threadIdx.x;
  size_t tokbase = (size_t)blockIdx.x * 64;

  // --- stage w_gate TRANSPOSED (wgt[e][h] = wg[h][e]) + x tile
  {
    float4 v = ((const float4*)wg)[t];   // wg[h = t>>1][e = (t&1)*4 + j]
    int h = t >> 1, e0 = (t & 1) * 4;
    wgt[(e0 + 0) * 128 + h] = v.x;       // 2-way bank alias only: free
    wgt[(e0 + 1) * 128 + h] = v.y;
    wgt[(e0 + 2) * 128 + h] = v.z;
    wgt[(e0 + 3) * 128 + h] = v.w;
  }
  {
    const float4* xsrc = (const float4*)(x + tokbase * HDIM);
#pragma unroll
    for (int i = 0; i < 8; ++i){
      int idx = i * 256 + t;
      int tok = idx >> 5, c = idx & 31;
      *(float4*)&xs[tok * 132 + c * 4] = xsrc[idx];
    }
  }
  __syncthreads();

  // --- conversion-source reads (regs for the bf16 frag build; dead before e-loop)
  float4 cv[8];
#pragma unroll
  for (int i = 0; i < 8; ++i)
    cv[i] = *(float4*)&xs[(t >> 2) * 132 + (t & 3) * 32 + i * 4];

  // --- gating: ALL threads. thread t -> token t&63, expert pair (2w, 2w+1).
  // wgt reads are wave-uniform (w = t>>6 constant per wave) -> LDS broadcast.
  // Summation order per expert identical to prior rounds (no top-k flip risk).
  {
    int tok = t & 63;
    const float* w0 = wgt + (t >> 6) * 2 * 128;
    const float* w1 = w0 + 128;
    float lg0 = 0.0f, lg1 = 0.0f;
#pragma unroll 8
    for (int c = 0; c < 32; ++c){
      float4 v = *(float4*)&xs[tok * 132 + c * 4];
      lg0 += v.x * w0[c * 4] + v.y * w0[c * 4 + 1] + v.z * w0[c * 4 + 2] + v.w * w0[c * 4 + 3];
      lg1 += v.x * w1[c * 4] + v.y * w1[c * 4 + 1] + v.z * w1[c * 4 + 2] + v.w * w1[c * 4 + 3];
    }
    int e0 = (t >> 6) * 2;
    glds[e0 * 64 + tok] = lg0;           // lanes have distinct tok: conflict-free
    glds[(e0 + 1) * 64 + tok] = lg1;
  }
  __syncthreads();   // xs reads (cv + gating) done; all logits in glds

  // --- top-2 + softmax (wave 0; column t is thread-exclusive: in-place safe)
  if (t < 64){
    float lg[8];
#pragma unroll
    for (int e = 0; e < 8; ++e) lg[e] = glds[e * 64 + t];
    int i1 = 0; float v1 = lg[0];
#pragma unroll
    for (int e = 1; e < 8; ++e) if (lg[e] > v1){ v1 = lg[e]; i1 = e; }
    int i2 = -1; float v2 = -3.4e38f;
#pragma unroll
    for (int e = 0; e < 8; ++e) if (e != i1 && lg[e] > v2){ v2 = lg[e]; i2 = e; }
    float ex = __expf(v2 - v1);
    float inv = 1.0f / (1.0f + ex);
#pragma unroll
    for (int e = 0; e < 8; ++e)
      glds[e * 64 + t] = (e == i1) ? inv : ((e == i2) ? ex * inv : 0.0f);
  }

  // --- convert f32 regs -> bf16 B-frags (overlaid on xs; xs dead now)
  // B-frag: B[k=(lane>>5)*8+j][n=lane&31] = x[token=tg*32+(lane&31)][h=kt*16+k]
  {
    int tokL = t >> 2, q = t & 3, tg = tokL >> 5;
#pragma unroll
    for (int jb = 0; jb < 4; ++jb){
      int h0 = q * 32 + jb * 8;
      int kt = h0 >> 4;
      int lslot = (tokL & 31) + 32 * ((h0 >> 3) & 1);
      float4 a = cv[2 * jb], b = cv[2 * jb + 1];
      unsigned long long lo = (unsigned long long)f2bf(a.x)
                            | ((unsigned long long)f2bf(a.y) << 16)
                            | ((unsigned long long)f2bf(a.z) << 32)
                            | ((unsigned long long)f2bf(a.w) << 48);
      unsigned long long hi = (unsigned long long)f2bf(b.x)
                            | ((unsigned long long)f2bf(b.y) << 16)
                            | ((unsigned long long)f2bf(b.z) << 32)
                            | ((unsigned long long)f2bf(b.w) << 48);
      unsigned long long* dst =
        (unsigned long long*)&frag[(((tg * 9) + kt) * 64 + lslot) * 8];
      dst[0] = lo; dst[1] = hi;
    }
    // bias kt=8 slots: 128 slots (2 tg x 64 l)
    if (t < 128){
      int btg = t >> 6, bl = t & 63;
      unsigned long long* dst =
        (unsigned long long*)&frag[(((btg * 9) + 8) * 64 + bl) * 8];
      dst[0] = (bl < 32) ? 0x3F80ull : 0ull;   // bf16 1.0 at j==0, k<8 half
      dst[1] = 0ull;
    }
  }
  __syncthreads();   // frags + gates ready

  // --- Phase B: MFMA. C[o][token] = sum_h W[h][o] * x[token][h]
  // B-frags are re-read from LDS per expert (frees 72 held regs; reads are
  // conflict-free: lane l reads bytes [l*16, l*16+16) of a 1KB-contiguous tile).
  int w = t >> 6, l = t & 63, l32 = l & 31, lh = l >> 5;

  f32x16 zero16;
#pragma unroll
  for (int i = 0; i < 16; ++i) zero16[i] = 0.0f;
  f32x16 tot0 = zero16, tot1 = zero16;

  const bf16x8* pwp = (const bf16x8*)pw;
#pragma unroll 1
  for (int e = 0; e < 8; ++e){
    float g0 = glds[e * 64 + l32];        // 2-way broadcast pair: free
    float g1 = glds[e * 64 + 32 + l32];
    const bf16x8* ap = pwp + ((size_t)(e * 4 + w) * 9) * 64 + l;
    f32x16 p0 = zero16, p1 = zero16;
#pragma unroll
    for (int kt = 0; kt < 9; ++kt){
      bf16x8 a  = ap[kt * 64];            // 1 KB/wave contiguous L2 stream
      bf16x8 b0 = *(const bf16x8*)&frag[((0 * 9 + kt) * 64 + l) * 8];
      bf16x8 b1 = *(const bf16x8*)&frag[((1 * 9 + kt) * 64 + l) * 8];
      p0 = __builtin_amdgcn_mfma_f32_32x32x16_bf16(a, b0, p0, 0, 0, 0);
      p1 = __builtin_amdgcn_mfma_f32_32x32x16_bf16(a, b1, p1, 0, 0, 0);
    }
#pragma unroll
    for (int r = 0; r < 16; ++r){         // static indices only
      tot0[r] += g0 * p0[r];
      tot1[r] += g1 * p1[r];
    }
  }
  __syncthreads();   // all frag reads done -> tb overlay safe

  // --- epilogue: LDS transpose (XOR swizzle) -> coalesced stores
  // C/D map: token(col)=l32, o(row)=w*32 + rg*8 + lh*4 + rr
  {
#pragma unroll
    for (int rg = 0; rg < 4; ++rg){
      int o = w * 32 + rg * 8 + lh * 4;
      {
        int trow = 0 * 32 + l32;
        int cs = (o >> 2) ^ l32;
        *(float4*)&tb[trow * 128 + cs * 4] =
          make_float4(tot0[rg * 4 + 0], tot0[rg * 4 + 1], tot0[rg * 4 + 2], tot0[rg * 4 + 3]);
      }
      {
        int trow = 1 * 32 + l32;
        int cs = (o >> 2) ^ l32;
        *(float4*)&tb[trow * 128 + cs * 4] =
          make_float4(tot1[rg * 4 + 0], tot1[rg * 4 + 1], tot1[rg * 4 + 2], tot1[rg * 4 + 3]);
      }
    }
  }
  __syncthreads();
#pragma unroll
  for (int i = 0; i < 8; ++i){
    int idx = i * 256 + t;
    int trow = idx >> 5, c = idx & 31;
    int cs = c ^ (trow & 31);
    float4 v = *(float4*)&tb[trow * 128 + cs * 4];
    *(float4*)(out + (tokbase + trow) * ODIM + c * 4) = v;
  }
}

// ---------------------------------------------------------------------------
extern "C" void kernel_launch(void* const* d_in, const int* in_sizes, int n_in,
                              void* d_out, int out_size, void* d_ws, size_t ws_size,
                              hipStream_t stream){
  const float* x  = (const float*)d_in[0];
  const float* wg = (const float*)d_in[1];
  // d_in[2] = w_noise (inactive in eval mode)
  const float* we = (const float*)d_in[3];
  const float* be = (const float*)d_in[4];
  // d_in[5] = top_k (== 2, baked in)
  float* out = (float*)d_out;

  unsigned short* pw = (unsigned short*)d_ws;          // 294,912 B

  pack_w   <<<72,   256, 0, stream>>>(we, be, pw);
  moe_fused<<<2048, 256, 0, stream>>>(x, wg, pw, out);
}

// Round 3
// 152.772 us; speedup vs baseline: 1.3602x; 1.3602x over previous
//
#include <hip/hip_runtime.h>
#include <math.h>

typedef __bf16 bf16x8 __attribute__((ext_vector_type(8)));
typedef float f32x16 __attribute__((ext_vector_type(16)));

#define NTOK 131072
#define HDIM 128
#define ODIM 128
#define NEXP 8
// K padded to 9 kt-steps of 16: kt 0..7 = real H, kt 8 = bias row (x side = 1.0)

__device__ __forceinline__ unsigned short f2bf(float f){
  union { float f; unsigned u; } v; v.f = f;
  unsigned r = v.u + 0x7FFFu + ((v.u >> 16) & 1u);
  return (unsigned short)(r >> 16);
}

// ---------------------------------------------------------------------------
// Kernel 1: pack W into A-operand fragment layout (transposed GEMM: A[m=o][k=h])
// pw flat: [e][mt(4)][kt(9)][lane(64)][j(8)] bf16
// A-frag (v_mfma_f32_32x32x16_bf16): A[m=lane&31][k=(lane>>5)*8+j]
// kt==8: k-local 0 row = b_expert[e][o], rest zero.
__global__ void pack_w(const float* __restrict__ we, const float* __restrict__ be,
                       unsigned short* __restrict__ pw){
  int f = blockIdx.x * 256 + threadIdx.x;      // 0..18431
  int l  = f & 63;
  int kt = (f >> 6) % 9;
  int emt = f / (64 * 9);
  int mt = emt & 3;
  int e  = emt >> 2;
  int o  = (mt << 5) + (l & 31);
  unsigned short vals[8];
#pragma unroll
  for (int j = 0; j < 8; ++j){
    int kl = ((l >> 5) << 3) + j;
    float v;
    if (kt < 8){
      int h = kt * 16 + kl;
      v = we[(e * HDIM + h) * ODIM + o];
    } else {
      v = (kl == 0) ? be[e * ODIM + o] : 0.0f;
    }
    vals[j] = f2bf(v);
  }
  *(bf16x8*)(pw + (size_t)f * 8) = *(bf16x8*)vals;
}

// ---------------------------------------------------------------------------
// Kernel 2: FUSED gating + MoE FFN. 64 tokens/block, 256 threads (4 waves).
// LDS 39 KiB: xs f32 (33 KiB; later overlaid by bf16 frags (18 KiB), then by
// f32 transpose buf (32 KiB)) + wgt 4 KiB ([e][h] transposed, reads broadcast)
// + glds 2 KiB ([e][token]; holds logits, then overwritten in-place by gates).
// R6 (occupancy, take 2): R5's (256,4) bound capped waves at 128 regs; with
// 64 accumulator regs (tot0/1 + p0/1) the compiler got 64 arch VGPRs and
// SPILLED (WRITE_SIZE 65536->141312 KB). Register floor is ~64 acc + ~90 arch
// = ~155/wave -> fits the 3-waves/SIMD budget (170), not 4. This round:
// identical body, __launch_bounds__(256,3) -> 3 blocks/CU (LDS 3x39936 =
// 117 KiB <= 160 KiB). Spill tripwire: WRITE_SIZE must be exactly 65536 KB.
// CRITICAL (R1-R3 lesson): accumulators are NAMED vars (tot0/tot1), every loop
// touching register arrays fully unrolled — dynamic indexing put tot in scratch
// (537 MB/launch of spill writes = the entire mystery WRITE_SIZE).
__launch_bounds__(256, 3)
__global__ void moe_fused(const float* __restrict__ x, const float* __restrict__ wg,
                          const unsigned short* __restrict__ pw, float* __restrict__ out){
  __shared__ char lds[33792 + 4096 + 2048];
  float* xs            = (float*)lds;                 // [tok(64)][132] f32
  unsigned short* frag = (unsigned short*)lds;        // overlay: [tg2][kt9][l64][j8]
  float* tb            = (float*)lds;                 // overlay: [trow64][128] f32
  float* wgt           = (float*)(lds + 33792);       // [e8][h128] f32 (transposed)
  float* glds          = (float*)(lds + 33792 + 4096);// [e8][tok64] f32

  int t = threadIdx.x;
  size_t tokbase = (size_t)blockIdx.x * 64;

  // --- stage w_gate TRANSPOSED (wgt[e][h] = wg[h][e]) + x tile
  {
    float4 v = ((const float4*)wg)[t];   // wg[h = t>>1][e = (t&1)*4 + j]
    int h = t >> 1, e0 = (t & 1) * 4;
    wgt[(e0 + 0) * 128 + h] = v.x;       // 2-way bank alias only: free
    wgt[(e0 + 1) * 128 + h] = v.y;
    wgt[(e0 + 2) * 128 + h] = v.z;
    wgt[(e0 + 3) * 128 + h] = v.w;
  }
  {
    const float4* xsrc = (const float4*)(x + tokbase * HDIM);
#pragma unroll
    for (int i = 0; i < 8; ++i){
      int idx = i * 256 + t;
      int tok = idx >> 5, c = idx & 31;
      *(float4*)&xs[tok * 132 + c * 4] = xsrc[idx];
    }
  }
  __syncthreads();

  // --- conversion-source reads (regs for the bf16 frag build; dead before e-loop)
  float4 cv[8];
#pragma unroll
  for (int i = 0; i < 8; ++i)
    cv[i] = *(float4*)&xs[(t >> 2) * 132 + (t & 3) * 32 + i * 4];

  // --- gating: ALL threads. thread t -> token t&63, expert pair (2w, 2w+1).
  // wgt reads are wave-uniform (w = t>>6 constant per wave) -> LDS broadcast.
  // Summation order per expert identical to prior rounds (no top-k flip risk).
  {
    int tok = t & 63;
    const float* w0 = wgt + (t >> 6) * 2 * 128;
    const float* w1 = w0 + 128;
    float lg0 = 0.0f, lg1 = 0.0f;
#pragma unroll 8
    for (int c = 0; c < 32; ++c){
      float4 v = *(float4*)&xs[tok * 132 + c * 4];
      lg0 += v.x * w0[c * 4] + v.y * w0[c * 4 + 1] + v.z * w0[c * 4 + 2] + v.w * w0[c * 4 + 3];
      lg1 += v.x * w1[c * 4] + v.y * w1[c * 4 + 1] + v.z * w1[c * 4 + 2] + v.w * w1[c * 4 + 3];
    }
    int e0 = (t >> 6) * 2;
    glds[e0 * 64 + tok] = lg0;           // lanes have distinct tok: conflict-free
    glds[(e0 + 1) * 64 + tok] = lg1;
  }
  __syncthreads();   // xs reads (cv + gating) done; all logits in glds

  // --- top-2 + softmax (wave 0; column t is thread-exclusive: in-place safe)
  if (t < 64){
    float lg[8];
#pragma unroll
    for (int e = 0; e < 8; ++e) lg[e] = glds[e * 64 + t];
    int i1 = 0; float v1 = lg[0];
#pragma unroll
    for (int e = 1; e < 8; ++e) if (lg[e] > v1){ v1 = lg[e]; i1 = e; }
    int i2 = -1; float v2 = -3.4e38f;
#pragma unroll
    for (int e = 0; e < 8; ++e) if (e != i1 && lg[e] > v2){ v2 = lg[e]; i2 = e; }
    float ex = __expf(v2 - v1);
    float inv = 1.0f / (1.0f + ex);
#pragma unroll
    for (int e = 0; e < 8; ++e)
      glds[e * 64 + t] = (e == i1) ? inv : ((e == i2) ? ex * inv : 0.0f);
  }

  // --- convert f32 regs -> bf16 B-frags (overlaid on xs; xs dead now)
  // B-frag: B[k=(lane>>5)*8+j][n=lane&31] = x[token=tg*32+(lane&31)][h=kt*16+k]
  {
    int tokL = t >> 2, q = t & 3, tg = tokL >> 5;
#pragma unroll
    for (int jb = 0; jb < 4; ++jb){
      int h0 = q * 32 + jb * 8;
      int kt = h0 >> 4;
      int lslot = (tokL & 31) + 32 * ((h0 >> 3) & 1);
      float4 a = cv[2 * jb], b = cv[2 * jb + 1];
      unsigned long long lo = (unsigned long long)f2bf(a.x)
                            | ((unsigned long long)f2bf(a.y) << 16)
                            | ((unsigned long long)f2bf(a.z) << 32)
                            | ((unsigned long long)f2bf(a.w) << 48);
      unsigned long long hi = (unsigned long long)f2bf(b.x)
                            | ((unsigned long long)f2bf(b.y) << 16)
                            | ((unsigned long long)f2bf(b.z) << 32)
                            | ((unsigned long long)f2bf(b.w) << 48);
      unsigned long long* dst =
        (unsigned long long*)&frag[(((tg * 9) + kt) * 64 + lslot) * 8];
      dst[0] = lo; dst[1] = hi;
    }
    // bias kt=8 slots: 128 slots (2 tg x 64 l)
    if (t < 128){
      int btg = t >> 6, bl = t & 63;
      unsigned long long* dst =
        (unsigned long long*)&frag[(((btg * 9) + 8) * 64 + bl) * 8];
      dst[0] = (bl < 32) ? 0x3F80ull : 0ull;   // bf16 1.0 at j==0, k<8 half
      dst[1] = 0ull;
    }
  }
  __syncthreads();   // frags + gates ready

  // --- Phase B: MFMA. C[o][token] = sum_h W[h][o] * x[token][h]
  // B-frags are re-read from LDS per expert (frees 72 held regs; reads are
  // conflict-free: lane l reads bytes [l*16, l*16+16) of a 1KB-contiguous tile).
  int w = t >> 6, l = t & 63, l32 = l & 31, lh = l >> 5;

  f32x16 zero16;
#pragma unroll
  for (int i = 0; i < 16; ++i) zero16[i] = 0.0f;
  f32x16 tot0 = zero16, tot1 = zero16;

  const bf16x8* pwp = (const bf16x8*)pw;
#pragma unroll 1
  for (int e = 0; e < 8; ++e){
    float g0 = glds[e * 64 + l32];        // 2-way broadcast pair: free
    float g1 = glds[e * 64 + 32 + l32];
    const bf16x8* ap = pwp + ((size_t)(e * 4 + w) * 9) * 64 + l;
    f32x16 p0 = zero16, p1 = zero16;
#pragma unroll
    for (int kt = 0; kt < 9; ++kt){
      bf16x8 a  = ap[kt * 64];            // 1 KB/wave contiguous L2 stream
      bf16x8 b0 = *(const bf16x8*)&frag[((0 * 9 + kt) * 64 + l) * 8];
      bf16x8 b1 = *(const bf16x8*)&frag[((1 * 9 + kt) * 64 + l) * 8];
      p0 = __builtin_amdgcn_mfma_f32_32x32x16_bf16(a, b0, p0, 0, 0, 0);
      p1 = __builtin_amdgcn_mfma_f32_32x32x16_bf16(a, b1, p1, 0, 0, 0);
    }
#pragma unroll
    for (int r = 0; r < 16; ++r){         // static indices only
      tot0[r] += g0 * p0[r];
      tot1[r] += g1 * p1[r];
    }
  }
  __syncthreads();   // all frag reads done -> tb overlay safe

  // --- epilogue: LDS transpose (XOR swizzle) -> coalesced stores
  // C/D map: token(col)=l32, o(row)=w*32 + rg*8 + lh*4 + rr
  {
#pragma unroll
    for (int rg = 0; rg < 4; ++rg){
      int o = w * 32 + rg * 8 + lh * 4;
      {
        int trow = 0 * 32 + l32;
        int cs = (o >> 2) ^ l32;
        *(float4*)&tb[trow * 128 + cs * 4] =
          make_float4(tot0[rg * 4 + 0], tot0[rg * 4 + 1], tot0[rg * 4 + 2], tot0[rg * 4 + 3]);
      }
      {
        int trow = 1 * 32 + l32;
        int cs = (o >> 2) ^ l32;
        *(float4*)&tb[trow * 128 + cs * 4] =
          make_float4(tot1[rg * 4 + 0], tot1[rg * 4 + 1], tot1[rg * 4 + 2], tot1[rg * 4 + 3]);
      }
    }
  }
  __syncthreads();
#pragma unroll
  for (int i = 0; i < 8; ++i){
    int idx = i * 256 + t;
    int trow = idx >> 5, c = idx & 31;
    int cs = c ^ (trow & 31);
    float4 v = *(float4*)&tb[trow * 128 + cs * 4];
    *(float4*)(out + (tokbase + trow) * ODIM + c * 4) = v;
  }
}

// ---------------------------------------------------------------------------
extern "C" void kernel_launch(void* const* d_in, const int* in_sizes, int n_in,
                              void* d_out, int out_size, void* d_ws, size_t ws_size,
                              hipStream_t stream){
  const float* x  = (const float*)d_in[0];
  const float* wg = (const float*)d_in[1];
  // d_in[2] = w_noise (inactive in eval mode)
  const float* we = (const float*)d_in[3];
  const float* be = (const float*)d_in[4];
  // d_in[5] = top_k (== 2, baked in)
  float* out = (float*)d_out;

  unsigned short* pw = (unsigned short*)d_ws;          // 294,912 B

  pack_w   <<<72,   256, 0, stream>>>(we, be, pw);
  moe_fused<<<2048, 256, 0, stream>>>(x, wg, pw, out);
}